// Round 7
// baseline (98.899 us; speedup 1.0000x reference)
//
#include <hip/hip_runtime.h>

// Problem dims (static, match reference)
#define N_PIX (512*512)
#define NFEAT 8
#define NCLUS 8
#define NB    4
#define GRIDX 128                 // blocks per sample; 512 blocks total = 2/CU exact fit
#define NBLOCKS (GRIDX*NB)        // 512
#define NCHUNK (N_PIX/4)          // 65536 float4/int4 chunks per sample
#define STRIDE (GRIDX*256)        // 32768 -> compile-time 2 iterations/thread
#define NITER  (NCHUNK/STRIDE)    // 2

// Workspace layout (floats):
//   P[e][b][r] at e*512 + b*128 + r  (72 entries: 64 sums f*8+c, 8 counts)
#define PART_TOTAL (72*NB*GRIDX)          // 36864
#define DIST_OFF  PART_TOTAL              // 512 per-block dist partials (packed)
#define S2_OFF    (DIST_OFF + NBLOCKS)    // 4*72 per-sample totals
#define MEAN_OFF  (S2_OFF + NB*72)        // 4*64 published means
#define CTR_OFF   (MEAN_OFF + NB*64)      // 37920 floats -> byte 151680 (64B-aligned)
// uint view at CTR_OFF: arr[b]=u[b*16], elect=u[64], flag[b]=u[80+b*16]
#define CLR_BYTES (9*64)                  // 576 B memset (counters + flags)

// Lessons ledger:
//  r3: __threadfence per block/barrier (1024 L2 wb+inv) -> 99 us kernel.
//  r4: all-blocks uncached re-fold = 19.1 MB coherence traffic = 52 of 56 us.
//      KEY FACT: everything else (Phase A + barrier + distance + epilogue)
//      measured ~4 us -> pred is L3-resident, algorithm is worth <10 us.
//  r5: per-entry float atomic totals = 128 serialized same-address RMWs x
//      288 lines -> serialization tail. Int counters (512 adds, r4/r6) are
//      fast; float RMW reduction is not.
//  => owner-fold: address-distinct write-through partials; 4 owner blocks
//     fold+publish means; 508 blocks spin a flag and read 64 floats each.

__device__ __forceinline__ void agent_st(float* p, float v) {
    __hip_atomic_store(p, v, __ATOMIC_RELAXED, __HIP_MEMORY_SCOPE_AGENT);
}
__device__ __forceinline__ float agent_ld(const float* p) {
    return __hip_atomic_load((float*)p, __ATOMIC_RELAXED, __HIP_MEMORY_SCOPE_AGENT);
}
__device__ __forceinline__ void agent_st_u(unsigned* p, unsigned v) {
    __hip_atomic_store(p, v, __ATOMIC_RELAXED, __HIP_MEMORY_SCOPE_AGENT);
}
__device__ __forceinline__ unsigned agent_ld_u(const unsigned* p) {
    return __hip_atomic_load((unsigned*)p, __ATOMIC_RELAXED, __HIP_MEMORY_SCOPE_AGENT);
}

__global__ __launch_bounds__(256, 2) void k_fused(const float* __restrict__ pred,
                                                  const int* __restrict__ tgt,
                                                  float* __restrict__ ws,
                                                  float* __restrict__ out) {
    __shared__ float ssum[4][64];
    __shared__ float scnt[4][8];
    __shared__ float pp[72][4];
    __shared__ float raw[72];
    __shared__ float mean[NCLUS * 9];
    __shared__ float slv[4];
    __shared__ int   is_last;
    __shared__ float sd[256];
    __shared__ float meanL[NB][64];
    __shared__ float slf[NB];

    const int tid = threadIdx.x;
    const int bx = blockIdx.x, b = blockIdx.y;
    const int lane = tid & 63, w = tid >> 6;
    unsigned* u = (unsigned*)(ws + CTR_OFF);
    unsigned* arr   = u + b * 16;        // per-sample arrival counter (own line)
    unsigned* elect = u + 64;            // global election counter
    unsigned* flag  = u + 80 + b * 16;   // per-sample fold-done flag (own line)

    const int4*   t4 = (const int4*)(tgt + b * N_PIX);
    const float4* p4 = (const float4*)(pred + (size_t)b * NFEAT * N_PIX);

    // ---- Phase A: pixel pass (bit-exact vs r0's k_sums) -------------------
    int   gss[NITER][4];
    float prs[NITER][NFEAT][4];
#pragma unroll
    for (int it = 0; it < NITER; ++it) {
        const int i = bx * 256 + tid + it * STRIDE;
        int4 g4 = t4[i];
        gss[it][0] = g4.x; gss[it][1] = g4.y; gss[it][2] = g4.z; gss[it][3] = g4.w;
#pragma unroll
        for (int f = 0; f < NFEAT; ++f) {
            float4 v = p4[f * NCHUNK + i];
            prs[it][f][0] = v.x; prs[it][f][1] = v.y;
            prs[it][f][2] = v.z; prs[it][f][3] = v.w;
        }
    }

    float acc[64];
#pragma unroll
    for (int i = 0; i < 64; ++i) acc[i] = 0.0f;
    int cnt[8] = {0, 0, 0, 0, 0, 0, 0, 0};

#pragma unroll
    for (int it = 0; it < NITER; ++it) {
#pragma unroll
        for (int j = 0; j < 4; ++j) {
            float m[NCLUS];
#pragma unroll
            for (int c = 0; c < NCLUS; ++c) {
                bool hit = (gss[it][j] == c);
                m[c] = hit ? 1.0f : 0.0f;
                cnt[c] += (int)__popcll(__ballot(hit));
            }
#pragma unroll
            for (int f = 0; f < NFEAT; ++f)
#pragma unroll
                for (int c = 0; c < NCLUS; ++c)
                    acc[f * 8 + c] = fmaf(m[c], prs[it][f][j], acc[f * 8 + c]);
        }
    }

    // Reduce-scatter butterfly: acc[0] = wave total of entry 'lane'.
#pragma unroll
    for (int k = 0; k < 6; ++k) {
        const int d = 1 << k;
        const int bit = (lane >> k) & 1;
#pragma unroll
        for (int p = 0; p < (64 >> 1); ++p) {
            if (p >= (64 >> (k + 1))) break;
            float a  = __shfl_xor(acc[2 * p],     d, 64);
            float vb = __shfl_xor(acc[2 * p + 1], d, 64);
            float own = bit ? acc[2 * p + 1] : acc[2 * p];
            float oth = bit ? vb : a;
            acc[p] = own + oth;
        }
    }

    ssum[w][lane] = acc[0];
    if (lane == 0) {
#pragma unroll
        for (int c = 0; c < NCLUS; ++c) scnt[w][c] = (float)cnt[c];
    }
    __syncthreads();
    if (tid < 72) {
        float s;
        if (tid < 64) s = ssum[0][tid] + ssum[1][tid] + ssum[2][tid] + ssum[3][tid];
        else { int c2 = tid - 64; s = scnt[0][c2] + scnt[1][c2] + scnt[2][c2] + scnt[3][c2]; }
        // write-through, address-distinct: visible to owner's uncached reads
        agent_st(&ws[tid * (NB * GRIDX) + b * GRIDX + bx], s);
    }
    __syncthreads();   // each wave drains vmcnt before barrier -> stores acked

    // ---- arrival (int fetch_add: proven fast in r4/r6) --------------------
    if (tid == 0)
        __hip_atomic_fetch_add(arr, 1u, __ATOMIC_RELAXED, __HIP_MEMORY_SCOPE_AGENT);

    if (bx == 0) {
        // ---- OWNER: wait 128 arrivals, fold, publish means+totals, flag ----
        if (tid == 0) {
            int guard = 0;
            while (agent_ld_u(arr) < (unsigned)GRIDX) {
                __builtin_amdgcn_s_sleep(2);
                if (++guard > (1 << 22)) break;   // fail loudly, never hang
            }
        }
        __syncthreads();
        // fold 72x128 partials; association tree == r0/r4 (verified 0.0)
        for (int s = tid; s < 288; s += 256) {
            const int e = s >> 2, q = s & 3;
            const float* src = ws + e * (NB * GRIDX) + b * GRIDX + q * 32;
            float t[32];
#pragma unroll
            for (int k2 = 0; k2 < 32; ++k2) t[k2] = agent_ld(src + k2);
            float uu[8];
#pragma unroll
            for (int k2 = 0; k2 < 8; ++k2)
                uu[k2] = ((t[4 * k2] + t[4 * k2 + 1]) + t[4 * k2 + 2]) + t[4 * k2 + 3];
            float r0 = uu[0] + uu[1], r1 = uu[2] + uu[3];
            float r2 = uu[4] + uu[5], r3 = uu[6] + uu[7];
            pp[e][q] = (r0 + r1) + (r2 + r3);
        }
        __syncthreads();
        if (tid < 72) {
            float s = (pp[tid][0] + pp[tid][1]) + (pp[tid][2] + pp[tid][3]);
            raw[tid] = s;
            agent_st(&ws[S2_OFF + b * 72 + tid], s);   // totals for epilogue
        }
        __syncthreads();
        if (tid < 64) {
            const int f = tid >> 3, c = tid & 7;
            float mv = raw[f * 8 + c] / raw[64 + c];
            mean[c * 9 + f] = mv;                       // stride-9: conflict-free
            agent_st(&ws[MEAN_OFF + b * 64 + tid], mv); // publish
        }
        __syncthreads();   // drains S2 + mean stores in every wave
        if (tid == 0) {
            asm volatile("s_waitcnt vmcnt(0)" ::: "memory");
            agent_st_u(flag, 1u);                       // release readers
        }
    } else {
        // ---- NON-OWNER: spin flag, read 64 means ---------------------------
        if (tid == 0) {
            int guard = 0;
            while (agent_ld_u(flag) != 1u) {
                __builtin_amdgcn_s_sleep(2);
                if (++guard > (1 << 22)) break;   // fail loudly, never hang
            }
        }
        __syncthreads();
        if (tid < 64) {
            float mv = agent_ld(&ws[MEAN_OFF + b * 64 + tid]);
            mean[(tid & 7) * 9 + (tid >> 3)] = mv;
        }
    }
    __syncthreads();

    // ---- Phase B: distance loop (pred is L3-resident; remat is cheap) -----
    float local = 0.0f;
#pragma unroll
    for (int it = 0; it < NITER; ++it) {
#pragma unroll
        for (int j = 0; j < 4; ++j) {
            const float* mm = &mean[gss[it][j] * 9];
            float dsq = 0.0f;
#pragma unroll
            for (int f = 0; f < NFEAT; ++f) {
                float d = mm[f] - prs[it][f][j];
                dsq = fmaf(d, d, dsq);
            }
            float diff = sqrtf(dsq);
            float dm = fminf(fmaxf(diff - 0.5f, 0.0f), 100000.0f);
            local = fmaf(dm, dm, local);
        }
    }

#pragma unroll
    for (int o = 32; o >= 1; o >>= 1) local += __shfl_xor(local, o, 64);
    if ((tid & 63) == 0) slv[tid >> 6] = local;
    __syncthreads();

    // ---- dist publication + election (512 int adds: fast) ------------------
    if (tid == 0) {
        agent_st(&ws[DIST_OFF + bx * NB + b], slv[0] + slv[1] + slv[2] + slv[3]);
        asm volatile("s_waitcnt vmcnt(0)" ::: "memory");
        unsigned old = __hip_atomic_fetch_add(elect, 1u, __ATOMIC_RELAXED,
                                              __HIP_MEMORY_SCOPE_AGENT);
        is_last = (old == (unsigned)(NBLOCKS - 1));
    }
    __syncthreads();
    if (!is_last) return;

    // ---- Phase C: epilogue by the single last block (r6 verbatim) ----------
    sd[tid] = agent_ld(ws + DIST_OFF + tid) + agent_ld(ws + DIST_OFF + 256 + tid);
    __syncthreads();
#pragma unroll
    for (int off = 128; off >= 4; off >>= 1) {
        if (tid < off) sd[tid] += sd[tid + off];
        __syncthreads();
    }
    // sd[0..3] = per-sample dist totals (index mod 4 == b preserved)

    const int bb = tid >> 6, idx = tid & 63;
    const float* S2 = ws + S2_OFF + bb * 72;
    meanL[bb][idx] = agent_ld(S2 + idx) / agent_ld(S2 + 64 + (idx & 7));
    __syncthreads();

    const int ii = idx >> 3, jj = idx & 7;
    float pdsq = 0.0f;
#pragma unroll
    for (int f = 0; f < 8; ++f) {
        float d = meanL[bb][f * 8 + ii] - meanL[bb][f * 8 + jj];
        pdsq = fmaf(d, d, pdsq);
    }
    float nrm = sqrtf(pdsq);
    float t = fminf(fmaxf(3.0f - nrm, 0.0f), 100000.0f);   // margin = 2*delta_d
    float val = (ii == jj) ? 0.0f : t * t * (1.0f / 56.0f); // / (C*(C-1))

    if (ii == 0) {
        float rsq = 0.0f;
#pragma unroll
        for (int f = 0; f < 8; ++f) {
            float m2 = meanL[bb][f * 8 + jj];
            rsq = fmaf(m2, m2, rsq);
        }
        float invc = 1.0f / agent_ld(S2 + 64 + jj);
        val += 0.001f * sqrtf(rsq) * 0.125f + sd[bb] * invc * 0.125f;
    }

#pragma unroll
    for (int o = 32; o >= 1; o >>= 1) val += __shfl_xor(val, o, 64);
    if (idx == 0) slf[bb] = val;
    __syncthreads();
    if (tid == 0) out[0] = (slf[0] + slf[1] + slf[2] + slf[3]) * 0.25f;
}

// ---------------------------------------------------------------------------
extern "C" void kernel_launch(void* const* d_in, const int* in_sizes, int n_in,
                              void* d_out, int out_size, void* d_ws, size_t ws_size,
                              hipStream_t stream) {
    const float* pred = (const float*)d_in[0];
    const int*   tgt  = (const int*)d_in[1];
    float* out = (float*)d_out;
    float* ws  = (float*)d_ws;

    // Zero counters + flags (ws is poisoned each iteration). 576-B node.
    hipMemsetAsync((char*)d_ws + (size_t)CTR_OFF * sizeof(float), 0,
                   CLR_BYTES, stream);

    dim3 grid(GRIDX, NB);   // 512 blocks = 2/CU exact co-residency
    k_fused<<<grid, 256, 0, stream>>>(pred, tgt, ws, out);
}

// Round 8
// 87.477 us; speedup vs baseline: 1.1306x; 1.1306x over previous
//
#include <hip/hip_runtime.h>

// Problem dims (static, match reference)
#define N_PIX (512*512)
#define NFEAT 8
#define NCLUS 8
#define NB    4
#define GRIDX 128                 // blocks per sample; 512 blocks total = 2/CU
#define NCHUNK (N_PIX/4)          // 65536 float4/int4 chunks per sample
#define STRIDE (GRIDX*256)        // 32768 -> compile-time 2 iterations/thread
// Workspace layout (floats). Partials transposed for contiguous fold:
//   P[e][b][r] at e*512 + b*128 + r,  e in [0,72): 64 sums (f*8+c) + 8 counts
#define PART_TOTAL (72*NB*GRIDX)          // 36864
#define DIST_OFF  PART_TOTAL              // 512 per-block dist partials
#define S2_OFF    (DIST_OFF + NB*GRIDX)   // staged per-sample totals, stride 72
// Every ws location we read is written earlier in the same call -> no init
// needed; safe against the harness 0xAA poison.
//
// SESSION VERDICT (rounds 1-7): this 3-kernel structure is the measured
// optimum. Alternatives tried and rejected with counter evidence:
//  - cooperative launch: not graph-capturable (silent no-op, r2).
//  - fused + __threadfence barrier: 1024 L2 wb/inv storms -> 99 us (r3).
//  - fused + uncached all-block refold: 19.1 MB coherence traffic (r4).
//  - fused + float atomic totals: same-address RMW serialization (r5).
//  - k_final folded into k_var via election: 92.6 vs 89.0 (r6).
//  - owner-fold + flag spin: 98.9 (r7).
// The kernel-boundary is the cheapest grid barrier on gfx950; the two input
// passes are algebraically mandatory (clip inside l_var needs means first);
// pass 2 is L3-resident. Remaining time = harness fill (43.5 us @ 77% HBM
// peak) + fixed per-iteration dispatch overhead, both outside kernel control.

// ---------------------------------------------------------------------------
// Pass A: per-sample per-cluster feature sums + counts.
// Register select-FMA accumulation (no atomics), ballot counts, 6-round
// reduce-scatter butterfly (lane L ends with wave total of entry L), block
// fold via LDS, plain transposed stores. (math identical to round 2,
// absmax 0.0)
// ---------------------------------------------------------------------------
__global__ __launch_bounds__(256) void k_sums(const float* __restrict__ pred,
                                              const int* __restrict__ tgt,
                                              float* __restrict__ ws) {
    const int tid = threadIdx.x;
    const int bx = blockIdx.x, b = blockIdx.y;
    const int lane = tid & 63, w = tid >> 6;

    float acc[64];
#pragma unroll
    for (int i = 0; i < 64; ++i) acc[i] = 0.0f;
    int cnt[8] = {0, 0, 0, 0, 0, 0, 0, 0};

    const int4*   t4 = (const int4*)(tgt + b * N_PIX);
    const float4* p4 = (const float4*)(pred + (size_t)b * NFEAT * N_PIX);

#pragma unroll
    for (int it = 0; it < NCHUNK / STRIDE; ++it) {
        const int i = bx * 256 + tid + it * STRIDE;
        int4 g4 = t4[i];
        int gs[4] = {g4.x, g4.y, g4.z, g4.w};
        float pr[NFEAT][4];
#pragma unroll
        for (int f = 0; f < NFEAT; ++f) {
            float4 v = p4[f * NCHUNK + i];
            pr[f][0] = v.x; pr[f][1] = v.y; pr[f][2] = v.z; pr[f][3] = v.w;
        }
#pragma unroll
        for (int j = 0; j < 4; ++j) {
            float m[NCLUS];
#pragma unroll
            for (int c = 0; c < NCLUS; ++c) {
                bool hit = (gs[j] == c);
                m[c] = hit ? 1.0f : 0.0f;
                cnt[c] += (int)__popcll(__ballot(hit));
            }
#pragma unroll
            for (int f = 0; f < NFEAT; ++f)
#pragma unroll
                for (int c = 0; c < NCLUS; ++c)
                    acc[f * 8 + c] = fmaf(m[c], pr[f][j], acc[f * 8 + c]);
        }
    }

    // Reduce-scatter butterfly: after 6 rounds acc[0] = wave total of entry
    // 'lane'.
#pragma unroll
    for (int k = 0; k < 6; ++k) {
        const int d = 1 << k;
        const int bit = (lane >> k) & 1;
#pragma unroll
        for (int p = 0; p < (64 >> 1); ++p) {
            if (p >= (64 >> (k + 1))) break;
            float a  = __shfl_xor(acc[2 * p],     d, 64);
            float bb = __shfl_xor(acc[2 * p + 1], d, 64);
            float own = bit ? acc[2 * p + 1] : acc[2 * p];
            float oth = bit ? bb : a;
            acc[p] = own + oth;
        }
    }

    __shared__ float ssum[4][64];
    __shared__ float scnt[4][8];
    ssum[w][lane] = acc[0];
    if (lane == 0) {
#pragma unroll
        for (int c = 0; c < NCLUS; ++c) scnt[w][c] = (float)cnt[c];
    }
    __syncthreads();

    if (tid < 72) {
        float s;
        if (tid < 64) s = ssum[0][tid] + ssum[1][tid] + ssum[2][tid] + ssum[3][tid];
        else { int c = tid - 64; s = scnt[0][c] + scnt[1][c] + scnt[2][c] + scnt[3][c]; }
        ws[tid * (NB * GRIDX) + b * GRIDX + bx] = s;   // transposed plain store
    }
}

// ---------------------------------------------------------------------------
// Pass B: Sum clip(||mu_g - p|| - 0.5, 0, 1e5)^2 over pixels.
// Prologue: 288 (entry,quad) slots over 256 threads fold 32 contiguous
// partials each via 8 independent float4 loads (chain depth 8, was 128).
// Means in LDS stride-9 pad (banks 9g+f distinct over g -> conflict-free).
// Epilogue: plain store of the block's dist partial. NO atomics anywhere.
// ---------------------------------------------------------------------------
__global__ __launch_bounds__(256) void k_var(const float* __restrict__ pred,
                                             const int* __restrict__ tgt,
                                             float* __restrict__ ws) {
    __shared__ float pp[72][4];
    __shared__ float raw[72];
    __shared__ float mean[NCLUS * 9];
    __shared__ float sl[4];
    const int tid = threadIdx.x;
    const int bx = blockIdx.x, b = blockIdx.y;

    for (int s = tid; s < 288; s += 256) {
        const int e = s >> 2, q = s & 3;
        const float4* src = (const float4*)(ws + e * (NB * GRIDX) + b * GRIDX) + q * 8;
        float4 a0 = src[0], a1 = src[1], a2 = src[2], a3 = src[3];
        float4 a4 = src[4], a5 = src[5], a6 = src[6], a7 = src[7];
        float r0 = (a0.x + a0.y + a0.z + a0.w) + (a1.x + a1.y + a1.z + a1.w);
        float r1 = (a2.x + a2.y + a2.z + a2.w) + (a3.x + a3.y + a3.z + a3.w);
        float r2 = (a4.x + a4.y + a4.z + a4.w) + (a5.x + a5.y + a5.z + a5.w);
        float r3 = (a6.x + a6.y + a6.z + a6.w) + (a7.x + a7.y + a7.z + a7.w);
        pp[e][q] = (r0 + r1) + (r2 + r3);
    }
    __syncthreads();
    if (tid < 72) {
        float s = (pp[tid][0] + pp[tid][1]) + (pp[tid][2] + pp[tid][3]);
        raw[tid] = s;
        if (bx == 0) ws[S2_OFF + b * 72 + tid] = s;   // stage for k_final
    }
    __syncthreads();
    if (tid < 64) {
        const int f = tid >> 3, c = tid & 7;
        mean[c * 9 + f] = raw[f * 8 + c] / raw[64 + c];
    }
    __syncthreads();

    const int4*   t4 = (const int4*)(tgt + b * N_PIX);
    const float4* p4 = (const float4*)(pred + (size_t)b * NFEAT * N_PIX);

    float local = 0.0f;
#pragma unroll
    for (int it = 0; it < NCHUNK / STRIDE; ++it) {
        const int i = bx * 256 + tid + it * STRIDE;
        int4 g4 = t4[i];
        int gs[4] = {g4.x, g4.y, g4.z, g4.w};
        float pr[NFEAT][4];
#pragma unroll
        for (int f = 0; f < NFEAT; ++f) {
            float4 v = p4[f * NCHUNK + i];
            pr[f][0] = v.x; pr[f][1] = v.y; pr[f][2] = v.z; pr[f][3] = v.w;
        }
#pragma unroll
        for (int j = 0; j < 4; ++j) {
            const float* m = &mean[gs[j] * 9];
            float dsq = 0.0f;
#pragma unroll
            for (int f = 0; f < NFEAT; ++f) {
                float d = m[f] - pr[f][j];
                dsq = fmaf(d, d, dsq);
            }
            float diff = sqrtf(dsq);
            float dm = fminf(fmaxf(diff - 0.5f, 0.0f), 100000.0f);
            local = fmaf(dm, dm, local);
        }
    }

#pragma unroll
    for (int o = 32; o >= 1; o >>= 1) local += __shfl_xor(local, o, 64);
    if ((tid & 63) == 0) sl[tid >> 6] = local;
    __syncthreads();
    if (tid == 0)
        ws[DIST_OFF + bx * NB + b] = sl[0] + sl[1] + sl[2] + sl[3];  // plain store
}

// ---------------------------------------------------------------------------
// Pass C: tiny epilogue, one block. Tree-reduces the 512 dist partials in LDS
// (stride multiples of 4 preserve the sample index b = idx&3), then the
// validated l_dist / l_reg / l_var-quirk math from round 2.
// ---------------------------------------------------------------------------
__global__ __launch_bounds__(256) void k_final(const float* __restrict__ ws,
                                               float* __restrict__ out) {
    __shared__ float sd[256];
    __shared__ float meanL[NB][64];
    __shared__ float sl[NB];
    const int tid = threadIdx.x;

    sd[tid] = ws[DIST_OFF + tid] + ws[DIST_OFF + 256 + tid];
    __syncthreads();
#pragma unroll
    for (int off = 128; off >= 4; off >>= 1) {
        if (tid < off) sd[tid] += sd[tid + off];
        __syncthreads();
    }
    // sd[0..3] = per-sample dist totals (index mod 4 == b preserved)

    const int b = tid >> 6, idx = tid & 63;
    const float* S2 = ws + S2_OFF + b * 72;
    meanL[b][idx] = S2[idx] / S2[64 + (idx & 7)];
    __syncthreads();

    const int i = idx >> 3, j = idx & 7;
    float pdsq = 0.0f;
#pragma unroll
    for (int f = 0; f < 8; ++f) {
        float d = meanL[b][f * 8 + i] - meanL[b][f * 8 + j];
        pdsq = fmaf(d, d, pdsq);
    }
    float nrm = sqrtf(pdsq);
    float t = fminf(fmaxf(3.0f - nrm, 0.0f), 100000.0f);   // margin = 2*delta_d
    float val = (i == j) ? 0.0f : t * t * (1.0f / 56.0f);  // / (C*(C-1))

    if (i == 0) {
        float rsq = 0.0f;
#pragma unroll
        for (int f = 0; f < 8; ++f) {
            float m = meanL[b][f * 8 + j];
            rsq = fmaf(m, m, rsq);
        }
        float invc = 1.0f / S2[64 + j];
        val += 0.001f * sqrtf(rsq) * 0.125f + sd[b] * invc * 0.125f;
    }

#pragma unroll
    for (int o = 32; o >= 1; o >>= 1) val += __shfl_xor(val, o, 64);
    if (idx == 0) sl[b] = val;
    __syncthreads();
    if (tid == 0) out[0] = (sl[0] + sl[1] + sl[2] + sl[3]) * 0.25f;
}

// ---------------------------------------------------------------------------
extern "C" void kernel_launch(void* const* d_in, const int* in_sizes, int n_in,
                              void* d_out, int out_size, void* d_ws, size_t ws_size,
                              hipStream_t stream) {
    const float* pred = (const float*)d_in[0];
    const int*   tgt  = (const int*)d_in[1];
    float* out = (float*)d_out;
    float* ws  = (float*)d_ws;

    dim3 grid(GRIDX, NB);   // 512 blocks, 2/CU
    k_sums<<<grid, 256, 0, stream>>>(pred, tgt, ws);
    k_var <<<grid, 256, 0, stream>>>(pred, tgt, ws);
    k_final<<<1, 256, 0, stream>>>(ws, out);
}